// Round 3
// baseline (151.290 us; speedup 1.0000x reference)
//
#include <hip/hip_runtime.h>

// EmbeddingDropout: out[t,:] = weight[x[t],:] * mask[x[t]]
// B*S = 16384 tokens, D = 512 fp32 (128 float4 per row).
//
// Structure: ONE WAVE = FOUR ROWS.
//  - x[t0..t0+3] is wave-uniform -> one scalar s_load_dwordx4 serves 4 rows,
//    amortizing the dependent index->row load chain 4x.
//  - Each lane issues 8 independent 16B weight loads (4 rows x cols {lane,
//    lane+64}) -> deep MLP per thread, latency fully hidden.
//  - Nontemporal stores: output is write-once; keep L2/L3 for the weight
//    table (103 MB, L3-resident) which has row reuse across duplicates.

typedef float v4f __attribute__((ext_vector_type(4)));

__global__ __launch_bounds__(256) void EmbeddingDropout_70592082477707_kernel(
    const int* __restrict__ x,        // [B*S] token ids (int32)
    const v4f* __restrict__ w,        // [V, D/4] weight as float4
    const float* __restrict__ mask,   // [V] per-row dropout scale
    v4f* __restrict__ out,            // [B*S, D/4]
    int n_tokens)                     // B*S
{
    int wave = (blockIdx.x * blockDim.x + threadIdx.x) >> 6;  // global wave id
    int lane = threadIdx.x & 63;
    int t0   = wave << 2;                                     // 4 rows / wave
    if (t0 >= n_tokens) return;

    // Wave-uniform token ids -> scalar loads (s_load_dwordx4 on x).
    int r0 = __builtin_amdgcn_readfirstlane(x[t0 + 0]);
    int r1 = __builtin_amdgcn_readfirstlane(x[t0 + 1]);
    int r2 = __builtin_amdgcn_readfirstlane(x[t0 + 2]);
    int r3 = __builtin_amdgcn_readfirstlane(x[t0 + 3]);

    float m0 = mask[r0];              // uniform addr -> scalar load
    float m1 = mask[r1];
    float m2 = mask[r2];
    float m3 = mask[r3];

    const v4f* __restrict__ s0 = w + (size_t)r0 * 128;
    const v4f* __restrict__ s1 = w + (size_t)r1 * 128;
    const v4f* __restrict__ s2 = w + (size_t)r2 * 128;
    const v4f* __restrict__ s3 = w + (size_t)r3 * 128;

    // 8 independent 16B loads in flight per lane.
    v4f a0 = s0[lane];  v4f b0 = s0[lane + 64];
    v4f a1 = s1[lane];  v4f b1 = s1[lane + 64];
    v4f a2 = s2[lane];  v4f b2 = s2[lane + 64];
    v4f a3 = s3[lane];  v4f b3 = s3[lane + 64];

    a0 *= m0; b0 *= m0;
    a1 *= m1; b1 *= m1;
    a2 *= m2; b2 *= m2;
    a3 *= m3; b3 *= m3;

    v4f* __restrict__ d0 = out + (size_t)(t0 + 0) * 128;
    v4f* __restrict__ d1 = out + (size_t)(t0 + 1) * 128;
    v4f* __restrict__ d2 = out + (size_t)(t0 + 2) * 128;
    v4f* __restrict__ d3 = out + (size_t)(t0 + 3) * 128;

    __builtin_nontemporal_store(a0, &d0[lane]);
    __builtin_nontemporal_store(b0, &d0[lane + 64]);
    __builtin_nontemporal_store(a1, &d1[lane]);
    __builtin_nontemporal_store(b1, &d1[lane + 64]);
    __builtin_nontemporal_store(a2, &d2[lane]);
    __builtin_nontemporal_store(b2, &d2[lane + 64]);
    __builtin_nontemporal_store(a3, &d3[lane]);
    __builtin_nontemporal_store(b3, &d3[lane + 64]);
}

extern "C" void kernel_launch(void* const* d_in, const int* in_sizes, int n_in,
                              void* d_out, int out_size, void* d_ws, size_t ws_size,
                              hipStream_t stream) {
    const int*   x    = (const int*)d_in[0];      // [B*S] int32
    const v4f*   w    = (const v4f*)d_in[1];      // [V, 512] fp32 -> float4
    const float* mask = (const float*)d_in[2];    // [V] fp32
    v4f*         out  = (v4f*)d_out;              // [B*S, 512] fp32 -> float4

    int n_tokens = out_size / 512;                // 8*2048 = 16384 rows
    int block = 256;                              // 4 waves x 4 rows = 16 rows/block
    int rows_per_block = 16;
    int grid = (n_tokens + rows_per_block - 1) / rows_per_block;  // 1024 blocks

    EmbeddingDropout_70592082477707_kernel<<<grid, block, 0, stream>>>(
        x, w, mask, out, n_tokens);
}